// Round 3
// baseline (193.318 us; speedup 1.0000x reference)
//
#include <hip/hip_runtime.h>
#include <math.h>

#define BB 8
#define HH 256
#define KK 256
#define EE 128

// DPP-based add: x + dpp_mov(x). Template args keep ctrl a compile-time const.
template <int CTRL, int RM>
__device__ __forceinline__ float dpp_add(float x) {
    int d = __builtin_amdgcn_update_dpp(0, __float_as_int(x), CTRL, RM, 0xf, true);
    return x + __int_as_float(d);
}
// Sum over each 32-lane half; valid in lanes 31 and 63.
__device__ __forceinline__ float dpp_reduce_half(float x) {
    x = dpp_add<0x111, 0xf>(x);  // row_shr:1
    x = dpp_add<0x112, 0xf>(x);  // row_shr:2
    x = dpp_add<0x114, 0xf>(x);  // row_shr:4
    x = dpp_add<0x118, 0xf>(x);  // row_shr:8
    x = dpp_add<0x142, 0xa>(x);  // row_bcast:15 -> lanes 31,63 hold 32-lane sums
    return x;
}
// Sum over all 64 lanes; valid in lane 63.
__device__ __forceinline__ float dpp_reduce_wave(float x) {
    x = dpp_reduce_half(x);
    x = dpp_add<0x143, 0xc>(x);  // row_bcast:31 -> lane 63 holds 64-lane sum
    return x;
}

// ---------------- Fused kernel: round-0 kvmn_bh + ticket-gated H-reduction. ----------------
// One block per (b,h), 256 threads = 4 waves. Phases 1-3 are bit-identical to
// the 102.7 us round-0 kernel. After the o_ws store, each block increments a
// per-b ticket (device scope, release); the 256th block for that b runs the
// reduction (bit-identical to the old kvmn_reduce) in-kernel, overlapping the
// tail of other b's compute and eliminating the separate reduce dispatch.
__global__ __launch_bounds__(256) void kvmn_fused(
    const float* __restrict__ hidden,     // [B,H,E]
    const float* __restrict__ key_emb,    // [VOCAB,E]
    const float* __restrict__ value_emb,  // [FVOCAB,E]
    const int*   __restrict__ key_seq,    // [B,K]
    const int*   __restrict__ value_seq,  // [B,H,K]
    const int*   __restrict__ mask,       // [B,H,K]
    float* __restrict__ o_ws,             // [B,H,E] workspace
    int*   __restrict__ done,             // [B] tickets (zeroed by memsetAsync)
    float* __restrict__ out)              // [B,E]
{
    __shared__ float  sh_u[KK];
    __shared__ float  sh_part[4];
    __shared__ float4 sh_o4[8][32];
    __shared__ float  sh_sum[256];
    __shared__ int    sh_cnt[256];
    __shared__ int    sh_ticket;

    const int bid  = blockIdx.x;
    const int b    = bid >> 8;           // / HH
    const int h    = bid & 255;          // % HH
    const int tid  = threadIdx.x;
    const int w    = tid >> 6;           // wave id 0..3
    const int lane = tid & 63;
    const int half = lane >> 5;          // which 32-lane half
    const int sub  = lane & 31;          // float4 granule within row (e = sub*4)

    // register-staged gather indices (one coalesced load each; k == tid)
    const int ksreg = key_seq[b * KK + tid];
    const int vsreg = value_seq[(size_t)(b * HH + h) * KK + tid];
    const int my_mask = mask[(size_t)(b * HH + h) * KK + tid];

    // per-lane hidden fragment for e = sub*4 .. sub*4+3
    const float4 h4 = *(const float4*)&hidden[(size_t)(b * HH + h) * EE + sub * 4];

    const float inv_scale = 0.08838834764831845f; // 1/sqrt(128)

    // ---- phase 1: u[k] = dot(hidden_row, key_emb[ks[k]])/sqrt(E)
    #pragma unroll 16
    for (int i = 0; i < 32; ++i) {
        const int    row = __shfl(ksreg, half * 32 + i, 64);
        const float4 kv  = *(const float4*)&key_emb[(size_t)row * EE + sub * 4];
        float part = kv.x * h4.x + kv.y * h4.y + kv.z * h4.z + kv.w * h4.w;
        part = dpp_reduce_half(part);           // VALU pipe, lanes 31/63 valid
        if (sub == 31) sh_u[w * 64 + half * 32 + i] = part * inv_scale;
    }
    __syncthreads();

    // ---- phase 2: d = exp(u)*mask; denom; p stays in REGISTER pk (lane k==tid)
    const float d = expf(sh_u[tid]) * (float)my_mask;
    float s = dpp_reduce_wave(d);
    if (lane == 63) sh_part[w] = s;
    __syncthreads();
    const float denom = sh_part[0] + sh_part[1] + sh_part[2] + sh_part[3];
    const float pk = d * (1.0f / (denom + 1e-10f));

    // ---- phase 3: o[e] = sum_k p[k]*value_emb[vs[k]][e]; idx+p via __shfl
    float4 acc = make_float4(0.f, 0.f, 0.f, 0.f);
    #pragma unroll 16
    for (int i = 0; i < 32; ++i) {
        const int    src = half * 32 + i;
        const float  p   = __shfl(pk, src, 64);
        const int    row = __shfl(vsreg, src, 64);
        const float4 v   = *(const float4*)&value_emb[(size_t)row * EE + sub * 4];
        acc.x += p * v.x;
        acc.y += p * v.y;
        acc.z += p * v.z;
        acc.w += p * v.w;
    }
    sh_o4[w * 2 + half][sub] = acc;
    __syncthreads();

    // ---- combine 8 partials, plain coalesced store
    if (tid < 32) {
        float4 t = sh_o4[0][tid];
        #pragma unroll
        for (int r = 1; r < 8; ++r) {
            const float4 q = sh_o4[r][tid];
            t.x += q.x; t.y += q.y; t.z += q.z; t.w += q.w;
        }
        *(float4*)&o_ws[(size_t)(b * HH + h) * EE + tid * 4] = t;
    }
    __syncthreads();   // o_ws store issued (barrier drains vmcnt)

    // ---- ticket: release our o row, count completions for this b
    if (tid == 0) {
        __threadfence();  // device-scope release of the o_ws writes
        sh_ticket = __hip_atomic_fetch_add(&done[b], 1, __ATOMIC_ACQ_REL,
                                           __HIP_MEMORY_SCOPE_AGENT);
    }
    __syncthreads();
    if (sh_ticket != HH - 1) return;

    // ---- last block for this b: all 256 o rows are released; reduce them.
    __threadfence();  // acquire: invalidate stale L1/L2 lines before reading o_ws
    {
        const int e  = tid & 127;
        const int hh = tid >> 7;
        float sum = 0.0f;
        int   cnt = 0;
        const float* base = o_ws + (size_t)(b * HH + hh * 128) * EE + e;
        #pragma unroll 8
        for (int hi = 0; hi < 128; ++hi) {
            const float v = base[(size_t)hi * EE];
            sum += v;
            cnt += (v != 0.0f) ? 1 : 0;
        }
        sh_sum[tid] = sum;
        sh_cnt[tid] = cnt;
        __syncthreads();
        if (tid < 128) {
            const float fs = sh_sum[tid] + sh_sum[tid + 128];
            const int   fc = sh_cnt[tid] + sh_cnt[tid + 128];
            out[b * EE + tid] = fs / (float)fc;
        }
    }
}

extern "C" void kernel_launch(void* const* d_in, const int* in_sizes, int n_in,
                              void* d_out, int out_size, void* d_ws, size_t ws_size,
                              hipStream_t stream) {
    const float* hidden    = (const float*)d_in[0];
    const float* key_emb   = (const float*)d_in[1];
    const float* value_emb = (const float*)d_in[2];
    const int*   key_seq   = (const int*)d_in[3];
    const int*   value_seq = (const int*)d_in[4];
    const int*   mask      = (const int*)d_in[5];

    float* o_ws = (float*)d_ws;                              // [B,H,E] = 1 MB
    int*   done = (int*)((char*)d_ws + (size_t)BB * HH * EE * sizeof(float));

    // tickets live in the poisoned workspace -> zero them each iteration
    hipMemsetAsync(done, 0, BB * sizeof(int), stream);

    kvmn_fused<<<BB * HH, 256, 0, stream>>>(hidden, key_emb, value_emb,
                                            key_seq, value_seq, mask,
                                            o_ws, done, (float*)d_out);
    (void)in_sizes; (void)n_in; (void)out_size; (void)ws_size;
}

// Round 4
// 115.366 us; speedup vs baseline: 1.6757x; 1.6757x over previous
//
#include <hip/hip_runtime.h>
#include <math.h>

#define BB 8
#define HH 256
#define KK 256
#define EE 128

// DPP-based add: x + dpp_mov(x). Template args keep ctrl a compile-time const.
template <int CTRL, int RM>
__device__ __forceinline__ float dpp_add(float x) {
    int d = __builtin_amdgcn_update_dpp(0, __float_as_int(x), CTRL, RM, 0xf, true);
    return x + __int_as_float(d);
}
// Sum over each 32-lane half; valid in lanes 31 and 63.
__device__ __forceinline__ float dpp_reduce_half(float x) {
    x = dpp_add<0x111, 0xf>(x);  // row_shr:1
    x = dpp_add<0x112, 0xf>(x);  // row_shr:2
    x = dpp_add<0x114, 0xf>(x);  // row_shr:4
    x = dpp_add<0x118, 0xf>(x);  // row_shr:8
    x = dpp_add<0x142, 0xa>(x);  // row_bcast:15 -> lanes 31,63 hold 32-lane sums
    return x;
}
// Sum over all 64 lanes; valid in lane 63.
__device__ __forceinline__ float dpp_reduce_wave(float x) {
    x = dpp_reduce_half(x);
    x = dpp_add<0x143, 0xc>(x);  // row_bcast:31 -> lane 63 holds 64-lane sum
    return x;
}

// ---------------- Kernel A: one block per (b,h), 256 threads = 4 waves. ----------------
// Issue-bound (R2 evidence: traffic cuts don't help), so this version minimizes
// per-thread instruction count vs round-0:
//  * phase 1: per-lane-own-k dot (k == tid). Lane streams its key row as 32
//    float4 loads (4 loads/cache line -> L1 absorbs); hidden row comes from an
//    LDS broadcast (uniform address, conflict-free). Removes 160 DPP adds +
//    32 ds_bpermute + the sh_u LDS round-trip; u stays in a register.
//  * phase 3: (p, voff) packed in LDS float2; 1 ds_read_b64 broadcast per k
//    instead of 2 ds_bpermute.
__global__ __launch_bounds__(256, 8) void kvmn_bh(
    const float* __restrict__ hidden,     // [B,H,E]
    const float* __restrict__ key_emb,    // [VOCAB,E]
    const float* __restrict__ value_emb,  // [FVOCAB,E]
    const int*   __restrict__ key_seq,    // [B,K]
    const int*   __restrict__ value_seq,  // [B,H,K]
    const int*   __restrict__ mask,       // [B,H,K]
    float* __restrict__ o_ws)             // [B,H,E]
{
    __shared__ float4 sh_h4[32];          // hidden row (128 floats)
    __shared__ float  sh_part[4];
    __shared__ float2 sh_pv[KK];          // (p_k, voff_k as float bits)
    __shared__ float4 sh_o4[8][32];

    const int bid  = blockIdx.x;
    const int b    = bid >> 8;           // / HH
    const int h    = bid & 255;          // % HH
    const int tid  = threadIdx.x;
    const int w    = tid >> 6;           // wave id 0..3
    const int lane = tid & 63;
    const int half = lane >> 5;          // which 32-lane half
    const int sub  = lane & 31;          // float4 granule within row (e = sub*4)

    const size_t bh = (size_t)(b * HH + h);

    // register-staged gather indices (one coalesced load each; k == tid)
    const int ksreg   = key_seq[b * KK + tid];
    const int vsreg   = value_seq[bh * KK + tid];
    const int my_mask = mask[bh * KK + tid];

    // stage hidden row for LDS broadcast
    if (tid < 32) sh_h4[tid] = *(const float4*)&hidden[bh * EE + tid * 4];
    __syncthreads();

    const float inv_scale = 0.08838834764831845f; // 1/sqrt(128)

    // ---- phase 1: u = dot(hidden_row, key_emb[ks[tid]]) / sqrt(E), k == tid.
    // Lane-private row stream: consecutive 16B loads share cache lines.
    const float* krow = &key_emb[(size_t)ksreg * EE];
    float4 acc1 = make_float4(0.f, 0.f, 0.f, 0.f);
    #pragma unroll 4
    for (int i = 0; i < 32; ++i) {
        const float4 kv = *(const float4*)&krow[i * 4];
        const float4 hv = sh_h4[i];                 // uniform addr -> broadcast
        acc1.x += kv.x * hv.x;
        acc1.y += kv.y * hv.y;
        acc1.z += kv.z * hv.z;
        acc1.w += kv.w * hv.w;
    }
    const float u = ((acc1.x + acc1.y) + (acc1.z + acc1.w)) * inv_scale;

    // ---- phase 2: d = exp(u)*mask; denom over 256 k; p stays per-lane (k==tid)
    const float d = expf(u) * (float)my_mask;
    float s = dpp_reduce_wave(d);
    if (lane == 63) sh_part[w] = s;
    __syncthreads();
    const float denom = sh_part[0] + sh_part[1] + sh_part[2] + sh_part[3];
    const float pk = d * (1.0f / (denom + 1e-10f));

    // publish (p, value-row offset) for the phase-3 broadcast loop
    sh_pv[tid] = make_float2(pk, __int_as_float(vsreg << 7));  // voff = vs*EE
    __syncthreads();

    // ---- phase 3: o[e] = sum_k p[k]*value_emb[vs[k]][e]
    // (w,half) handles k in [w*64 + half*32, +32); same order as round 0.
    float4 acc = make_float4(0.f, 0.f, 0.f, 0.f);
    const int kbase = w * 64 + half * 32;
    #pragma unroll 8
    for (int i = 0; i < 32; ++i) {
        const float2 pv = sh_pv[kbase + i];         // uniform addr -> broadcast
        const float  p  = pv.x;
        const int    ro = __float_as_int(pv.y);
        const float4 v  = *(const float4*)&value_emb[(size_t)ro + sub * 4];
        acc.x += p * v.x;
        acc.y += p * v.y;
        acc.z += p * v.z;
        acc.w += p * v.w;
    }
    sh_o4[w * 2 + half][sub] = acc;
    __syncthreads();

    // ---- combine 8 partials, plain coalesced store (no atomics)
    if (tid < 32) {
        float4 t = sh_o4[0][tid];
        #pragma unroll
        for (int r = 1; r < 8; ++r) {
            const float4 q = sh_o4[r][tid];
            t.x += q.x; t.y += q.y; t.z += q.z; t.w += q.w;
        }
        *(float4*)&o_ws[bh * EE + tid * 4] = t;
    }
}

// ---------------- Kernel B: reduce over H + nonzero-count average. ----------------
__global__ __launch_bounds__(256) void kvmn_reduce(
    const float* __restrict__ o_ws,      // [B,H,E]
    float* __restrict__ out)             // [B,E]
{
    __shared__ float sh_sum[256];
    __shared__ int   sh_cnt[256];

    const int b  = blockIdx.x;
    const int t  = threadIdx.x;
    const int e  = t & 127;
    const int hh = t >> 7;

    float sum = 0.0f;
    int   cnt = 0;
    const float* base = o_ws + (size_t)(b * HH + hh * 128) * EE + e;
    #pragma unroll 8
    for (int h = 0; h < 128; ++h) {
        const float v = base[(size_t)h * EE];
        sum += v;
        cnt += (v != 0.0f) ? 1 : 0;
    }
    sh_sum[t] = sum;
    sh_cnt[t] = cnt;
    __syncthreads();
    if (t < 128) {
        const float s = sh_sum[t] + sh_sum[t + 128];
        const int   c = sh_cnt[t] + sh_cnt[t + 128];
        out[b * EE + t] = s / (float)c;
    }
}

extern "C" void kernel_launch(void* const* d_in, const int* in_sizes, int n_in,
                              void* d_out, int out_size, void* d_ws, size_t ws_size,
                              hipStream_t stream) {
    const float* hidden    = (const float*)d_in[0];
    const float* key_emb   = (const float*)d_in[1];
    const float* value_emb = (const float*)d_in[2];
    const int*   key_seq   = (const int*)d_in[3];
    const int*   value_seq = (const int*)d_in[4];
    const int*   mask      = (const int*)d_in[5];

    float* o_ws = (float*)d_ws;   // 1 MB

    kvmn_bh<<<BB * HH, 256, 0, stream>>>(hidden, key_emb, value_emb,
                                         key_seq, value_seq, mask, o_ws);
    kvmn_reduce<<<BB, 256, 0, stream>>>(o_ws, (float*)d_out);
    (void)in_sizes; (void)n_in; (void)out_size; (void)ws_size;
}

// Round 5
// 103.452 us; speedup vs baseline: 1.8687x; 1.1152x over previous
//
#include <hip/hip_runtime.h>
#include <math.h>

#define BB 8
#define HH 256
#define KK 256
#define EE 128
#define GG 4   // h-values per block

// DPP-based add: x + dpp_mov(x). Template args keep ctrl a compile-time const.
template <int CTRL, int RM>
__device__ __forceinline__ float dpp_add(float x) {
    int d = __builtin_amdgcn_update_dpp(0, __float_as_int(x), CTRL, RM, 0xf, true);
    return x + __int_as_float(d);
}
// Sum over each 32-lane half; valid in lanes 31 and 63.
__device__ __forceinline__ float dpp_reduce_half(float x) {
    x = dpp_add<0x111, 0xf>(x);  // row_shr:1
    x = dpp_add<0x112, 0xf>(x);  // row_shr:2
    x = dpp_add<0x114, 0xf>(x);  // row_shr:4
    x = dpp_add<0x118, 0xf>(x);  // row_shr:8
    x = dpp_add<0x142, 0xa>(x);  // row_bcast:15 -> lanes 31,63 hold 32-lane sums
    return x;
}
// Sum over all 64 lanes; valid in lane 63.
__device__ __forceinline__ float dpp_reduce_wave(float x) {
    x = dpp_reduce_half(x);
    x = dpp_add<0x143, 0xc>(x);  // row_bcast:31 -> lane 63 holds 64-lane sum
    return x;
}

// ---------------- Kernel A: one block per (b, 4-h group), 256 threads. ----------------
// L2-traffic model: round-0 read 536 MB (268 MB key-gather repeated 256x/b +
// 268 MB irreducible value-gather) ~= the observed 16 us at 34.5 TB/s.
// Amortizing 4 h's per block cuts key-gather traffic 4x (268->67 MB) WITHOUT
// the extra dispatch that sank round 2. All gathers keep the verified
// coalesced pattern: each 32-lane half reads one full 512 B row per load
// (round 4 proved per-lane-own-row scattering is a 3.5x disaster).
// k-order, DPP order, and combine order are bit-identical to round 0.
__global__ __launch_bounds__(256) void kvmn_bh4(
    const float* __restrict__ hidden,     // [B,H,E]
    const float* __restrict__ key_emb,    // [VOCAB,E]
    const float* __restrict__ value_emb,  // [FVOCAB,E]
    const int*   __restrict__ key_seq,    // [B,K]
    const int*   __restrict__ value_seq,  // [B,H,K]
    const int*   __restrict__ mask,       // [B,H,K]
    float* __restrict__ o_ws)             // [B,H,E]
{
    __shared__ float  sh_u[GG][KK];       //  4 KB
    __shared__ float  sh_part[GG][4];
    __shared__ float2 sh_pv[GG][KK];      //  8 KB (p_k, voff_k bits)
    __shared__ float4 sh_o4[GG][8][32];   // 16 KB

    const int bid  = blockIdx.x;          // 0..511
    const int b    = bid >> 6;            // / 64
    const int h0   = (bid & 63) << 2;     // * GG
    const int tid  = threadIdx.x;
    const int w    = tid >> 6;            // wave id 0..3
    const int lane = tid & 63;
    const int half = lane >> 5;
    const int sub  = lane & 31;           // float4 granule within row

    // register-staged gather indices (coalesced; k == tid)
    const int ksreg = key_seq[b * KK + tid];
    int vs[GG], mk[GG];
    #pragma unroll
    for (int g = 0; g < GG; ++g) {
        vs[g] = value_seq[(size_t)(b * HH + h0 + g) * KK + tid];
        mk[g] = mask[(size_t)(b * HH + h0 + g) * KK + tid];
    }

    // per-lane hidden fragments for the 4 h's (e = sub*4 .. sub*4+3)
    float4 hq0 = *(const float4*)&hidden[(size_t)(b * HH + h0 + 0) * EE + sub * 4];
    float4 hq1 = *(const float4*)&hidden[(size_t)(b * HH + h0 + 1) * EE + sub * 4];
    float4 hq2 = *(const float4*)&hidden[(size_t)(b * HH + h0 + 2) * EE + sub * 4];
    float4 hq3 = *(const float4*)&hidden[(size_t)(b * HH + h0 + 3) * EE + sub * 4];

    const float inv_scale = 0.08838834764831845f; // 1/sqrt(128)

    // ---- phase 1: u[g][k] = dot(hidden[h0+g], key_emb[ks[k]])/sqrt(E)
    // One pass over the key rows feeds all 4 h's (the 4x traffic cut).
    #pragma unroll 8
    for (int i = 0; i < 32; ++i) {
        const int    k   = w * 64 + half * 32 + i;
        const int    row = __shfl(ksreg, half * 32 + i, 64);
        const float4 kv  = *(const float4*)&key_emb[(size_t)row * EE + sub * 4];
        float p0 = kv.x * hq0.x + kv.y * hq0.y + kv.z * hq0.z + kv.w * hq0.w;
        float p1 = kv.x * hq1.x + kv.y * hq1.y + kv.z * hq1.z + kv.w * hq1.w;
        float p2 = kv.x * hq2.x + kv.y * hq2.y + kv.z * hq2.z + kv.w * hq2.w;
        float p3 = kv.x * hq3.x + kv.y * hq3.y + kv.z * hq3.z + kv.w * hq3.w;
        p0 = dpp_reduce_half(p0) * inv_scale;   // same order as round 0
        p1 = dpp_reduce_half(p1) * inv_scale;
        p2 = dpp_reduce_half(p2) * inv_scale;
        p3 = dpp_reduce_half(p3) * inv_scale;
        if (sub == 31) {                        // lanes 31,63 hold the 2 k-sums
            sh_u[0][k] = p0;
            sh_u[1][k] = p1;
            sh_u[2][k] = p2;
            sh_u[3][k] = p3;
        }
    }
    __syncthreads();

    // ---- phase 2: per h, d = exp(u)*mask; denom; p published as (p, voff)
    float dreg[GG];
    #pragma unroll
    for (int g = 0; g < GG; ++g) {
        dreg[g] = expf(sh_u[g][tid]) * (float)mk[g];
        const float s = dpp_reduce_wave(dreg[g]);
        if (lane == 63) sh_part[g][w] = s;
    }
    __syncthreads();
    #pragma unroll
    for (int g = 0; g < GG; ++g) {
        const float denom = sh_part[g][0] + sh_part[g][1] + sh_part[g][2] + sh_part[g][3];
        const float pk    = dreg[g] * (1.0f / (denom + 1e-10f));
        sh_pv[g][tid] = make_float2(pk, __int_as_float(vs[g] << 7)); // voff = vs*EE
    }
    __syncthreads();

    // ---- phase 3: o[g][e] = sum_k p[k]*value_emb[vs[k]][e]
    // (w,half) handles k in [w*64 + half*32, +32); uniform-address ds_read_b64
    // broadcast of (p, voff); value-row reads stay 512 B contiguous per half.
    const int kbase = w * 64 + half * 32;
    #pragma unroll
    for (int g = 0; g < GG; ++g) {
        float4 acc = make_float4(0.f, 0.f, 0.f, 0.f);
        #pragma unroll 8
        for (int i = 0; i < 32; ++i) {
            const float2 pv = sh_pv[g][kbase + i];
            const float  p  = pv.x;
            const int    ro = __float_as_int(pv.y);
            const float4 v  = *(const float4*)&value_emb[(size_t)ro + sub * 4];
            acc.x += p * v.x;
            acc.y += p * v.y;
            acc.z += p * v.z;
            acc.w += p * v.w;
        }
        sh_o4[g][w * 2 + half][sub] = acc;
    }
    __syncthreads();

    // ---- combine 8 partials per h; coalesced 2 KB store across 128 threads
    if (tid < 128) {
        const int g   = tid >> 5;
        const int col = tid & 31;
        float4 t = sh_o4[g][0][col];
        #pragma unroll
        for (int r = 1; r < 8; ++r) {
            const float4 q = sh_o4[g][r][col];
            t.x += q.x; t.y += q.y; t.z += q.z; t.w += q.w;
        }
        *(float4*)&o_ws[(size_t)(b * HH + h0 + g) * EE + col * 4] = t;
    }
}

// ---------------- Kernel B: reduce over H + nonzero-count average. ----------------
__global__ __launch_bounds__(256) void kvmn_reduce(
    const float* __restrict__ o_ws,      // [B,H,E]
    float* __restrict__ out)             // [B,E]
{
    __shared__ float sh_sum[256];
    __shared__ int   sh_cnt[256];

    const int b  = blockIdx.x;
    const int t  = threadIdx.x;
    const int e  = t & 127;
    const int hh = t >> 7;

    float sum = 0.0f;
    int   cnt = 0;
    const float* base = o_ws + (size_t)(b * HH + hh * 128) * EE + e;
    #pragma unroll 8
    for (int h = 0; h < 128; ++h) {
        const float v = base[(size_t)h * EE];
        sum += v;
        cnt += (v != 0.0f) ? 1 : 0;
    }
    sh_sum[t] = sum;
    sh_cnt[t] = cnt;
    __syncthreads();
    if (t < 128) {
        const float s = sh_sum[t] + sh_sum[t + 128];
        const int   c = sh_cnt[t] + sh_cnt[t + 128];
        out[b * EE + t] = s / (float)c;
    }
}

extern "C" void kernel_launch(void* const* d_in, const int* in_sizes, int n_in,
                              void* d_out, int out_size, void* d_ws, size_t ws_size,
                              hipStream_t stream) {
    const float* hidden    = (const float*)d_in[0];
    const float* key_emb   = (const float*)d_in[1];
    const float* value_emb = (const float*)d_in[2];
    const int*   key_seq   = (const int*)d_in[3];
    const int*   value_seq = (const int*)d_in[4];
    const int*   mask      = (const int*)d_in[5];

    float* o_ws = (float*)d_ws;   // 1 MB

    kvmn_bh4<<<BB * (HH / GG), 256, 0, stream>>>(hidden, key_emb, value_emb,
                                                 key_seq, value_seq, mask, o_ws);
    kvmn_reduce<<<BB, 256, 0, stream>>>(o_ws, (float*)d_out);
    (void)in_sizes; (void)n_in; (void)out_size; (void)ws_size;
}

// Round 6
// 98.430 us; speedup vs baseline: 1.9640x; 1.0510x over previous
//
#include <hip/hip_runtime.h>
#include <math.h>

#define BB 8
#define HH 256
#define KK 256
#define EE 128

// DPP-based add: x + dpp_mov(x). Template args keep ctrl a compile-time const.
template <int CTRL, int RM>
__device__ __forceinline__ float dpp_add(float x) {
    int d = __builtin_amdgcn_update_dpp(0, __float_as_int(x), CTRL, RM, 0xf, true);
    return x + __int_as_float(d);
}
// Sum over each 32-lane half; valid in lanes 31 and 63.
__device__ __forceinline__ float dpp_reduce_half(float x) {
    x = dpp_add<0x111, 0xf>(x);  // row_shr:1
    x = dpp_add<0x112, 0xf>(x);  // row_shr:2
    x = dpp_add<0x114, 0xf>(x);  // row_shr:4
    x = dpp_add<0x118, 0xf>(x);  // row_shr:8
    x = dpp_add<0x142, 0xa>(x);  // row_bcast:15 -> lanes 31,63 hold 32-lane sums
    return x;
}
// Sum over all 64 lanes; valid in lane 63.
__device__ __forceinline__ float dpp_reduce_wave(float x) {
    x = dpp_reduce_half(x);
    x = dpp_add<0x143, 0xc>(x);  // row_bcast:31 -> lane 63 holds 64-lane sum
    return x;
}

// ---------------- Kernel A: one block per (b,h), 256 threads = 4 waves. ----------------
// Round-0 structure (best measured: 2048 blocks, full occupancy, coalesced
// half-wave row gathers) + ONE change: phase 3 skips masked-out k's.
// mask kills ~50% of p[k] exactly (p = 0.0f), so each (w,half) chunk compacts
// its (p, voff) pairs into LDS via ballot/popc and loops only over survivors:
//  * value-gather L2 traffic halves (268 -> ~134 MB) -- the only traffic on
//    the L2-resident path (value_emb = 512 KB, fits per-XCD L2; key path was
//    proven insensitive in R2/R5).
//  * phase-3 issue count ~halves.
// Bit-identical output: skipped terms contributed exactly +0.0f, surviving
// terms keep their relative order within each chunk, combine order unchanged.
__global__ __launch_bounds__(256) void kvmn_bh(
    const float* __restrict__ hidden,     // [B,H,E]
    const float* __restrict__ key_emb,    // [VOCAB,E]
    const float* __restrict__ value_emb,  // [FVOCAB,E]
    const int*   __restrict__ key_seq,    // [B,K]
    const int*   __restrict__ value_seq,  // [B,H,K]
    const int*   __restrict__ mask,       // [B,H,K]
    float* __restrict__ o_ws)             // [B,H,E]
{
    __shared__ float  sh_u[KK];
    __shared__ float  sh_part[4];
    __shared__ float2 sh_pv[8][32];      // per-(w,half) compacted (p, voff bits)
    __shared__ int    sh_cnt[8];
    __shared__ float4 sh_o4[8][32];

    const int bid  = blockIdx.x;
    const int b    = bid >> 8;           // / HH
    const int h    = bid & 255;          // % HH
    const int tid  = threadIdx.x;
    const int w    = tid >> 6;           // wave id 0..3
    const int lane = tid & 63;
    const int half = lane >> 5;          // which 32-lane half
    const int sub  = lane & 31;          // float4 granule within row (e = sub*4)
    const int chunk = tid >> 5;          // == w*2 + half, 0..7

    const size_t bh = (size_t)(b * HH + h);

    // register-staged gather indices (one coalesced load each; k == tid)
    const int ksreg   = key_seq[b * KK + tid];
    const int vsreg   = value_seq[bh * KK + tid];
    const int my_mask = mask[bh * KK + tid];

    // per-lane hidden fragment for e = sub*4 .. sub*4+3
    const float4 h4 = *(const float4*)&hidden[bh * EE + sub * 4];

    const float inv_scale = 0.08838834764831845f; // 1/sqrt(128)

    // ---- phase 1: u[k] = dot(hidden_row, key_emb[ks[k]])/sqrt(E)
    // (w, half) handles k in [w*64 + half*32, +32); row idx via __shfl broadcast.
    #pragma unroll 16
    for (int i = 0; i < 32; ++i) {
        const int    row = __shfl(ksreg, half * 32 + i, 64);
        const float4 kv  = *(const float4*)&key_emb[(size_t)row * EE + sub * 4];
        float part = kv.x * h4.x + kv.y * h4.y + kv.z * h4.z + kv.w * h4.w;
        part = dpp_reduce_half(part);           // VALU pipe, lanes 31/63 valid
        if (sub == 31) sh_u[w * 64 + half * 32 + i] = part * inv_scale;
    }
    __syncthreads();

    // ---- phase 2: d = exp(u)*mask; denom; p stays per-lane (k == tid)
    const float d = expf(sh_u[tid]) * (float)my_mask;
    float s = dpp_reduce_wave(d);
    if (lane == 63) sh_part[w] = s;
    __syncthreads();
    const float denom = sh_part[0] + sh_part[1] + sh_part[2] + sh_part[3];
    const float pk = d * (1.0f / (denom + 1e-10f));

    // ---- compact publish: per (w,half) chunk, keep only mask!=0 entries.
    const unsigned long long bal = __ballot(my_mask != 0);
    const unsigned hb  = (unsigned)(bal >> (half * 32));       // my half's bits
    const int      pos = __popc(hb & ((1u << sub) - 1u));      // exclusive rank
    if (my_mask) sh_pv[chunk][pos] = make_float2(pk, __int_as_float(vsreg << 7));
    if (sub == 0) sh_cnt[chunk] = __popc(hb);
    __syncthreads();

    // ---- phase 3: o[e] = sum over surviving k of p*value_emb[vs[k]][e]
    // uniform-address ds_read_b64 broadcast per entry; value-row reads stay
    // 512 B contiguous per half (the verified coalesced pattern).
    const int cnt = sh_cnt[chunk];
    float4 acc = make_float4(0.f, 0.f, 0.f, 0.f);
    #pragma unroll 4
    for (int i = 0; i < cnt; ++i) {
        const float2 pv = sh_pv[chunk][i];
        const float  p  = pv.x;
        const int    ro = __float_as_int(pv.y);
        const float4 v  = *(const float4*)&value_emb[(size_t)ro + sub * 4];
        acc.x += p * v.x;
        acc.y += p * v.y;
        acc.z += p * v.z;
        acc.w += p * v.w;
    }
    sh_o4[chunk][sub] = acc;
    __syncthreads();

    // ---- combine 8 partials, plain coalesced store (order identical to round 0)
    if (tid < 32) {
        float4 t = sh_o4[0][tid];
        #pragma unroll
        for (int r = 1; r < 8; ++r) {
            const float4 q = sh_o4[r][tid];
            t.x += q.x; t.y += q.y; t.z += q.z; t.w += q.w;
        }
        *(float4*)&o_ws[bh * EE + tid * 4] = t;
    }
}

// ---------------- Kernel B: reduce over H + nonzero-count average. ----------------
__global__ __launch_bounds__(256) void kvmn_reduce(
    const float* __restrict__ o_ws,      // [B,H,E]
    float* __restrict__ out)             // [B,E]
{
    __shared__ float sh_sum[256];
    __shared__ int   sh_cnt[256];

    const int b  = blockIdx.x;
    const int t  = threadIdx.x;
    const int e  = t & 127;
    const int hh = t >> 7;

    float sum = 0.0f;
    int   cnt = 0;
    const float* base = o_ws + (size_t)(b * HH + hh * 128) * EE + e;
    #pragma unroll 8
    for (int h = 0; h < 128; ++h) {
        const float v = base[(size_t)h * EE];
        sum += v;
        cnt += (v != 0.0f) ? 1 : 0;
    }
    sh_sum[t] = sum;
    sh_cnt[t] = cnt;
    __syncthreads();
    if (t < 128) {
        const float s = sh_sum[t] + sh_sum[t + 128];
        const int   c = sh_cnt[t] + sh_cnt[t + 128];
        out[b * EE + t] = s / (float)c;
    }
}

extern "C" void kernel_launch(void* const* d_in, const int* in_sizes, int n_in,
                              void* d_out, int out_size, void* d_ws, size_t ws_size,
                              hipStream_t stream) {
    const float* hidden    = (const float*)d_in[0];
    const float* key_emb   = (const float*)d_in[1];
    const float* value_emb = (const float*)d_in[2];
    const int*   key_seq   = (const int*)d_in[3];
    const int*   value_seq = (const int*)d_in[4];
    const int*   mask      = (const int*)d_in[5];

    float* o_ws = (float*)d_ws;   // 1 MB

    kvmn_bh<<<BB * HH, 256, 0, stream>>>(hidden, key_emb, value_emb,
                                         key_seq, value_seq, mask, o_ws);
    kvmn_reduce<<<BB, 256, 0, stream>>>(o_ws, (float*)d_out);
    (void)in_sizes; (void)n_in; (void)out_size; (void)ws_size;
}

// Round 7
// 92.431 us; speedup vs baseline: 2.0915x; 1.0649x over previous
//
#include <hip/hip_runtime.h>
#include <math.h>

#define BB 8
#define HH 256
#define KK 256
#define EE 128

// DPP-based add: x + dpp_mov(x). Template args keep ctrl a compile-time const.
template <int CTRL, int RM>
__device__ __forceinline__ float dpp_add(float x) {
    int d = __builtin_amdgcn_update_dpp(0, __float_as_int(x), CTRL, RM, 0xf, true);
    return x + __int_as_float(d);
}
// Sum over each 32-lane half; valid in lanes 31 and 63.
__device__ __forceinline__ float dpp_reduce_half(float x) {
    x = dpp_add<0x111, 0xf>(x);  // row_shr:1
    x = dpp_add<0x112, 0xf>(x);  // row_shr:2
    x = dpp_add<0x114, 0xf>(x);  // row_shr:4
    x = dpp_add<0x118, 0xf>(x);  // row_shr:8
    x = dpp_add<0x142, 0xa>(x);  // row_bcast:15 -> lanes 31,63 hold 32-lane sums
    return x;
}
// Sum over all 64 lanes; valid in lane 63.
__device__ __forceinline__ float dpp_reduce_wave(float x) {
    x = dpp_reduce_half(x);
    x = dpp_add<0x143, 0xc>(x);  // row_bcast:31 -> lane 63 holds 64-lane sum
    return x;
}

// ---------------- Kernel A: one block per (b,h), 256 threads = 4 waves. ----------------
// R6 proved the kernel is bound by per-thread issued work (R5: traffic cut
// neutral; R6: phase-3 work halved -> -4.3 us). This round pulls the same
// mask-compaction lever on phase 1: k's with mask==0 contribute d = 0.0f
// exactly, so their key-row load + 4 FMA + 5-DPP reduce chain are dead work.
// Compacting (ks, vs) per 32-lane half BEFORE phase 1 cuts its loop from 32
// to ~16-18 iterations. Bonus: the compacted layout makes all producer->
// consumer LDS hops within-half-wave, so only 2 barriers remain (denom
// reduce + final combine) vs 4.
// Bit-identical output: surviving u's use identical row data / FMA order /
// DPP chain; masked lanes held d = expf(u)*0.0f = 0.0f before, d = 0.0f now;
// reduce lane-positions and phase-3 compacted order are unchanged from R6.
__global__ __launch_bounds__(256) void kvmn_bh(
    const float* __restrict__ hidden,     // [B,H,E]
    const float* __restrict__ key_emb,    // [VOCAB,E]
    const float* __restrict__ value_emb,  // [FVOCAB,E]
    const int*   __restrict__ key_seq,    // [B,K]
    const int*   __restrict__ value_seq,  // [B,H,K]
    const int*   __restrict__ mask,       // [B,H,K]
    float* __restrict__ o_ws)             // [B,H,E]
{
    __shared__ float  sh_u[KK];          // compacted: u for chunk c at [c*32 + i]
    __shared__ float  sh_part[4];
    __shared__ int    sh_ki[8][32];      // compacted key row indices per chunk
    __shared__ float2 sh_pv[8][32];      // compacted (p, voff bits) per chunk
    __shared__ float4 sh_o4[8][32];

    const int bid  = blockIdx.x;
    const int b    = bid >> 8;           // / HH
    const int h    = bid & 255;          // % HH
    const int tid  = threadIdx.x;
    const int w    = tid >> 6;           // wave id 0..3
    const int lane = tid & 63;
    const int half = lane >> 5;          // which 32-lane half
    const int sub  = lane & 31;          // float4 granule within row (e = sub*4)
    const int chunk = tid >> 5;          // == w*2 + half, 0..7

    const size_t bh = (size_t)(b * HH + h);

    // register-staged gather indices (one coalesced load each; k == tid)
    const int ksreg   = key_seq[b * KK + tid];
    const int vsreg   = value_seq[bh * KK + tid];
    const int my_mask = mask[bh * KK + tid];

    // per-lane hidden fragment for e = sub*4 .. sub*4+3
    const float4 h4 = *(const float4*)&hidden[bh * EE + sub * 4];

    // ---- early mask compaction (per 32-lane half); cnt lives in a register
    const unsigned long long bal = __ballot(my_mask != 0);
    const unsigned hb  = (unsigned)(bal >> (half * 32));       // my half's bits
    const int      pos = __popc(hb & ((1u << sub) - 1u));      // exclusive rank
    const int      cnt = __popc(hb);                           // uniform in half
    if (my_mask) sh_ki[chunk][pos] = ksreg;
    // no barrier: sh_ki written and read by the same half-wave

    const float inv_scale = 0.08838834764831845f; // 1/sqrt(128)

    // ---- phase 1 (compacted): u_i = dot(hidden_row, key_emb[ki[i]])/sqrt(E)
    // Loop only over surviving k's (~16-18 incl. half-divergence max); each
    // iteration keeps the verified coalesced pattern: the half reads one full
    // 512 B row; row index via uniform-address LDS broadcast.
    #pragma unroll 4
    for (int i = 0; i < cnt; ++i) {
        const int    row = sh_ki[chunk][i];
        const float4 kv  = *(const float4*)&key_emb[(size_t)row * EE + sub * 4];
        float part = kv.x * h4.x + kv.y * h4.y + kv.z * h4.z + kv.w * h4.w;
        part = dpp_reduce_half(part);           // same chain/order as R0/R6
        if (sub == 31) sh_u[chunk * 32 + i] = part * inv_scale;
    }
    // no barrier: lane reads its own chunk's u (written by its half's lane 31)

    // ---- phase 2: d = exp(u) for survivors else 0; denom over 256 k
    float d = 0.0f;
    if (my_mask) d = expf(sh_u[chunk * 32 + pos]);
    float s = dpp_reduce_wave(d);               // same lane positions as before
    if (lane == 63) sh_part[w] = s;
    __syncthreads();                            // cross-wave: denom needs all 4
    const float denom = sh_part[0] + sh_part[1] + sh_part[2] + sh_part[3];
    const float pk = d * (1.0f / (denom + 1e-10f));

    // compacted publish (same order as R6); same-half write->read, no barrier
    if (my_mask) sh_pv[chunk][pos] = make_float2(pk, __int_as_float(vsreg << 7));

    // ---- phase 3: o[e] = sum over surviving k of p*value_emb[vs[k]][e]
    float4 acc = make_float4(0.f, 0.f, 0.f, 0.f);
    #pragma unroll 4
    for (int i = 0; i < cnt; ++i) {
        const float2 pv = sh_pv[chunk][i];      // uniform addr -> broadcast
        const float  p  = pv.x;
        const int    ro = __float_as_int(pv.y);
        const float4 v  = *(const float4*)&value_emb[(size_t)ro + sub * 4];
        acc.x += p * v.x;
        acc.y += p * v.y;
        acc.z += p * v.z;
        acc.w += p * v.w;
    }
    sh_o4[chunk][sub] = acc;
    __syncthreads();                            // cross-wave: combine reads all

    // ---- combine 8 partials, plain coalesced store (order identical to R0)
    if (tid < 32) {
        float4 t = sh_o4[0][tid];
        #pragma unroll
        for (int r = 1; r < 8; ++r) {
            const float4 q = sh_o4[r][tid];
            t.x += q.x; t.y += q.y; t.z += q.z; t.w += q.w;
        }
        *(float4*)&o_ws[bh * EE + tid * 4] = t;
    }
}

// ---------------- Kernel B: reduce over H + nonzero-count average. ----------------
__global__ __launch_bounds__(256) void kvmn_reduce(
    const float* __restrict__ o_ws,      // [B,H,E]
    float* __restrict__ out)             // [B,E]
{
    __shared__ float sh_sum[256];
    __shared__ int   sh_cnt[256];

    const int b  = blockIdx.x;
    const int t  = threadIdx.x;
    const int e  = t & 127;
    const int hh = t >> 7;

    float sum = 0.0f;
    int   cnt = 0;
    const float* base = o_ws + (size_t)(b * HH + hh * 128) * EE + e;
    #pragma unroll 8
    for (int h = 0; h < 128; ++h) {
        const float v = base[(size_t)h * EE];
        sum += v;
        cnt += (v != 0.0f) ? 1 : 0;
    }
    sh_sum[t] = sum;
    sh_cnt[t] = cnt;
    __syncthreads();
    if (t < 128) {
        const float s = sh_sum[t] + sh_sum[t + 128];
        const int   c = sh_cnt[t] + sh_cnt[t + 128];
        out[b * EE + t] = s / (float)c;
    }
}

extern "C" void kernel_launch(void* const* d_in, const int* in_sizes, int n_in,
                              void* d_out, int out_size, void* d_ws, size_t ws_size,
                              hipStream_t stream) {
    const float* hidden    = (const float*)d_in[0];
    const float* key_emb   = (const float*)d_in[1];
    const float* value_emb = (const float*)d_in[2];
    const int*   key_seq   = (const int*)d_in[3];
    const int*   value_seq = (const int*)d_in[4];
    const int*   mask      = (const int*)d_in[5];

    float* o_ws = (float*)d_ws;   // 1 MB

    kvmn_bh<<<BB * HH, 256, 0, stream>>>(hidden, key_emb, value_emb,
                                         key_seq, value_seq, mask, o_ws);
    kvmn_reduce<<<BB, 256, 0, stream>>>(o_ws, (float*)d_out);
    (void)in_sizes; (void)n_in; (void)out_size; (void)ws_size;
}